// Round 5
// baseline (879.760 us; speedup 1.0000x reference)
//
#include <hip/hip_runtime.h>
#include <stdint.h>

typedef __attribute__((ext_vector_type(8))) short bf16x8;
typedef __attribute__((ext_vector_type(4))) short s16x4;
typedef __attribute__((ext_vector_type(4))) float f32x4;

__device__ __forceinline__ short f2bf(float f){
  unsigned x = __float_as_uint(f);
  unsigned r = (x + 0x7fffu + ((x >> 16) & 1u)) >> 16;
  return (short)r;
}

// async global->LDS, 16B per lane (dest = wave-uniform base + lane*16)
__device__ __forceinline__ void g2l16(const void* g, void* l){
  __builtin_amdgcn_global_load_lds(
      (const __attribute__((address_space(1))) unsigned int*)(unsigned long long)(uintptr_t)g,
      (__attribute__((address_space(3))) unsigned int*)(unsigned int)(uintptr_t)l,
      16, 0, 0);
}

// ---------------------------------------------------------------------------
// f32 -> bf16 convert, 8 elems/thread
// ---------------------------------------------------------------------------
__global__ __launch_bounds__(256) void cvt_bf16(const float* __restrict__ in,
                                                short* __restrict__ out, int n8){
  const int i = blockIdx.x * 256 + threadIdx.x;
  if (i >= n8) return;
  const float4* p = (const float4*)in + (size_t)i * 2;
  const float4 a = p[0], b = p[1];
  bf16x8 v;
  v[0] = f2bf(a.x); v[1] = f2bf(a.y); v[2] = f2bf(a.z); v[3] = f2bf(a.w);
  v[4] = f2bf(b.x); v[5] = f2bf(b.y); v[6] = f2bf(b.z); v[7] = f2bf(b.w);
  *(bf16x8*)(out + (size_t)i * 8) = v;
}

// ---------------------------------------------------------------------------
// (mask || pad) -> bitmask. grid: (SK/256, B*SQ). 1 bit per (row, s).
// ---------------------------------------------------------------------------
__global__ __launch_bounds__(256)
void make_bits(const int* __restrict__ mask, const int* __restrict__ pad,
               unsigned* __restrict__ bits, int SK){
  const int s = blockIdx.x * 256 + threadIdx.x;
  const size_t row = blockIdx.y;               // b*512 + q
  const int b = (int)(row >> 9);
  const bool v = (mask[row * SK + s] != 0) || (pad[(size_t)b * SK + s] != 0);
  unsigned long long bal = __ballot(v);
  const int lane = threadIdx.x & 63;
  if ((lane & 31) == 0)
    bits[(row * SK + s) >> 5] = (unsigned)(bal >> (lane & 32));
}

// ---------------------------------------------------------------------------
// Pack 8 weights (f32, 1024x1024 row-major K x N) into bf16 tiles:
// packed[(nt*32+kt)*4096 + nl*32 + kl] = W[(kt*32+kl)*1024 + nt*128 + nl]
// grid: (256 tiles, 8 weights)
// ---------------------------------------------------------------------------
struct W8 { const float* w[8]; };
__global__ __launch_bounds__(256) void pack_w8(W8 ws8, short* __restrict__ out){
  const int m = blockIdx.y;
  const float* __restrict__ W = ws8.w[m];
  short* o = out + (size_t)m * 1048576 + (size_t)blockIdx.x * 4096;
  const int kt = blockIdx.x & 31, nt = blockIdx.x >> 5;
  const int t = threadIdx.x;
  #pragma unroll
  for (int i = 0; i < 16; ++i){
    int flat = i * 256 + t;              // 0..4095
    int kl = flat >> 7;                  // /128
    int nl = flat & 127;
    o[nl * 32 + kl] = f2bf(W[(size_t)(kt * 32 + kl) * 1024 + nt * 128 + nl]);
  }
}

// ---------------------------------------------------------------------------
// GEMM: C(M,1024) = A(M,1024)bf16 @ Wp + bias(f32). 128x256 tile, BK=32,
// 512 threads (8 waves of 64x64). A via global_load_lds with XOR-swizzled
// source column; sA read back with matching XOR. B tiles staged linearly.
// OM=0: C bf16 row-major. OM=1: C bf16 as (B,H=16,DK=64,S). OM=2: C f32.
// ---------------------------------------------------------------------------
template<int OM>
__global__ __launch_bounds__(512)
void gemm256(const short* __restrict__ A, const short* __restrict__ Wp,
             const float* __restrict__ bias, void* __restrict__ Cv, int S){
  __shared__ short sA[128 * 32];      // 8 KB
  __shared__ short sB[2 * 128 * 32];  // 16 KB (two 128-n tiles)
  const int t = threadIdx.x;
  const int m0 = blockIdx.x * 128;
  const int ny = blockIdx.y;           // 0..3
  const int n0 = ny * 256;
  const int w = t >> 6, lane = t & 63, lr = lane & 15, lg = lane >> 4;
  const int wm = (w >> 2) * 64, wn = (w & 3) * 64;

  const int arow = t >> 2, c4 = t & 3;
  const int swz = c4 ^ (arow & 3);
  const short* Ag = A + (size_t)(m0 + arow) * 1024 + swz * 8;
  const short* Bg = Wp + ((size_t)(ny * 2) * 32) * 4096 + t * 8;
  short* sAp = sA + t * 8;
  short* sBp = sB + t * 8;

  f32x4 acc[4][4] = {};

  for (int kt = 0; kt < 32; ++kt){
    __syncthreads();
    g2l16(Ag + kt * 32, sAp);
    const short* bt = Bg + (size_t)kt * 4096;
    g2l16(bt, sBp);
    g2l16(bt + 131072, sBp + 4096);
    __syncthreads();

    bf16x8 af[4], bfr[4];
    #pragma unroll
    for (int mi = 0; mi < 4; ++mi){
      const int row = wm + mi * 16 + lr;
      af[mi] = *(const bf16x8*)&sA[row * 32 + (lg ^ (row & 3)) * 8];
    }
    #pragma unroll
    for (int ni = 0; ni < 4; ++ni)
      bfr[ni] = *(const bf16x8*)&sB[(wn + ni * 16 + lr) * 32 + lg * 8];
    #pragma unroll
    for (int mi = 0; mi < 4; ++mi)
      #pragma unroll
      for (int ni = 0; ni < 4; ++ni)
        acc[mi][ni] = __builtin_amdgcn_mfma_f32_16x16x32_bf16(
            af[mi], bfr[ni], acc[mi][ni], 0, 0, 0);
  }

  #pragma unroll
  for (int ni = 0; ni < 4; ++ni){
    const int n = n0 + wn + ni * 16 + lr;
    const float bv = bias[n];
    #pragma unroll
    for (int mi = 0; mi < 4; ++mi){
      const int mb = m0 + wm + mi * 16 + lg * 4;
      if (OM == 0){
        short* C = (short*)Cv;
        #pragma unroll
        for (int j = 0; j < 4; ++j)
          C[(size_t)(mb + j) * 1024 + n] = f2bf(acc[mi][ni][j] + bv);
      } else if (OM == 1){
        short* C = (short*)Cv;
        const int bb = mb / S, sb = mb % S;
        const int hh = n >> 6, dk = n & 63;
        s16x4 pk;
        #pragma unroll
        for (int j = 0; j < 4; ++j) pk[j] = f2bf(acc[mi][ni][j] + bv);
        *(s16x4*)&C[(((size_t)bb * 16 + hh) * 64 + dk) * S + sb] = pk;
      } else {
        float* C = (float*)Cv;
        #pragma unroll
        for (int j = 0; j < 4; ++j)
          C[(size_t)(mb + j) * 1024 + n] = acc[mi][ni][j] + bv;
      }
    }
  }
}

// ---------------------------------------------------------------------------
// Flash attention. Block = (b, h, 128 q-rows), 8 waves (16 q each).
// MODE 0/1 (needs aw): two-phase — P1 stats (m,l), P2 recompute + aw + PV.
// MODE 2 (no aw): single-pass online-rescale flash.
// V read direct from global (L2-resident). K staged via global_load_lds,
// XOR-swizzled. P bounced through per-wave LDS for the PV A-operand.
// MODE: 0 scores = o ; 1 scores += 0.5*o ; 2 concat = bf16(scores + 0.5*o)
// ---------------------------------------------------------------------------
template<int SK, bool HAS_BIAS, int MODE>
__global__ __launch_bounds__(512)
void attn3(const short* __restrict__ Qp, const short* __restrict__ Kp,
           const short* __restrict__ Vt, const unsigned* __restrict__ bits,
           float* __restrict__ aw, float* __restrict__ scores,
           short* __restrict__ concat){
  constexpr int NT  = SK / 128;
  constexpr int SKW = SK / 32;
  __shared__ short sK[128 * 64];    // 16 KB
  __shared__ short sP[8 * 2048];    // 32 KB

  const int bid = blockIdx.x;
  const int qt = bid & 3, h = (bid >> 2) & 15, b = bid >> 6;
  const int t = threadIdx.x, w = t >> 6, lane = t & 63;
  const int lr = lane & 15, lg = lane >> 4;
  const int qw = qt * 128 + w * 16;

  const short* Qb = Qp + ((size_t)(b * 512 + qw + lr)) * 1024 + h * 64;
  bf16x8 qf[2];
  qf[0] = *(const bf16x8*)&Qb[lg * 8];
  qf[1] = *(const bf16x8*)&Qb[32 + lg * 8];

  const int kchunk = (lane & 7) ^ ((lane >> 3) & 7);
  const short* Ksrc = Kp + ((size_t)b * SK + w * 16 + (lane >> 3)) * 1024 + h * 64 + kchunk * 8;
  short* sKd = sK + w * 1024 + lane * 8;
  const short* Vb = Vt + ((size_t)(b * 16 + h)) * 64 * SK;
  short* sPw = sP + w * 2048;

  const unsigned* bitrow[4];
  if (HAS_BIAS){
    #pragma unroll
    for (int j = 0; j < 4; ++j)
      bitrow[j] = bits + ((size_t)(b * 512 + qw + lg * 4 + j)) * SKW;
  }

  float mrow[4], lrow[4];
  #pragma unroll
  for (int j = 0; j < 4; ++j){ mrow[j] = -3.4e38f; lrow[j] = 0.f; }
  f32x4 acco[4] = {};

  if (MODE != 2){
    // ---------------- Phase 1: stats ----------------
    for (int tt = 0; tt < NT; ++tt){
      const int s0 = tt * 128;
      __syncthreads();
      g2l16(Ksrc + (size_t)s0 * 1024, sKd);
      g2l16(Ksrc + (size_t)(s0 + 8) * 1024, sKd + 512);
      __syncthreads();

      f32x4 accs[8];
      #pragma unroll
      for (int si = 0; si < 8; ++si){
        f32x4 a = {};
        #pragma unroll
        for (int dt = 0; dt < 2; ++dt){
          bf16x8 kf = *(const bf16x8*)&sK[(si * 16 + lr) * 64 + ((dt * 4 + lg) ^ (lr & 7)) * 8];
          a = __builtin_amdgcn_mfma_f32_16x16x32_bf16(qf[dt], kf, a, 0, 0, 0);
        }
        accs[si] = a;
      }

      #pragma unroll
      for (int j = 0; j < 4; ++j){
        unsigned wb[4];
        if (HAS_BIAS){
          #pragma unroll
          for (int sp = 0; sp < 4; ++sp) wb[sp] = bitrow[j][tt * 4 + sp];
        }
        float vals[8];
        #pragma unroll
        for (int si = 0; si < 8; ++si){
          float v = accs[si][j] * 0.125f;
          if (HAS_BIAS && ((wb[si >> 1] >> ((si & 1) * 16 + lr)) & 1u)) v = -1e30f;
          vals[si] = v;
        }
        float mt = vals[0];
        #pragma unroll
        for (int si = 1; si < 8; ++si) mt = fmaxf(mt, vals[si]);
        const float mn = fmaxf(mrow[j], mt);
        float ssum = 0.f;
        #pragma unroll
        for (int si = 0; si < 8; ++si) ssum += __expf(vals[si] - mn);
        lrow[j] = lrow[j] * __expf(mrow[j] - mn) + ssum;
        mrow[j] = mn;
      }
    }

    #pragma unroll
    for (int j = 0; j < 4; ++j){
      #pragma unroll
      for (int d = 1; d < 16; d <<= 1){
        float mo = __shfl_xor(mrow[j], d);
        float lo = __shfl_xor(lrow[j], d);
        float mn = fmaxf(mrow[j], mo);
        lrow[j] = lrow[j] * __expf(mrow[j] - mn) + lo * __expf(mo - mn);
        mrow[j] = mn;
      }
    }
    float rinv[4];
    #pragma unroll
    for (int j = 0; j < 4; ++j) rinv[j] = 1.0f / lrow[j];

    // ---------------- Phase 2: aw + PV ----------------
    for (int tt = 0; tt < NT; ++tt){
      const int s0 = tt * 128;
      __syncthreads();
      g2l16(Ksrc + (size_t)s0 * 1024, sKd);
      g2l16(Ksrc + (size_t)(s0 + 8) * 1024, sKd + 512);
      __syncthreads();

      f32x4 accs[8];
      #pragma unroll
      for (int si = 0; si < 8; ++si){
        f32x4 a = {};
        #pragma unroll
        for (int dt = 0; dt < 2; ++dt){
          bf16x8 kf = *(const bf16x8*)&sK[(si * 16 + lr) * 64 + ((dt * 4 + lg) ^ (lr & 7)) * 8];
          a = __builtin_amdgcn_mfma_f32_16x16x32_bf16(qf[dt], kf, a, 0, 0, 0);
        }
        accs[si] = a;
      }

      #pragma unroll
      for (int j = 0; j < 4; ++j){
        unsigned wb[4];
        if (HAS_BIAS){
          #pragma unroll
          for (int sp = 0; sp < 4; ++sp) wb[sp] = bitrow[j][tt * 4 + sp];
        }
        const int qq = lg * 4 + j;
        float* awrow = aw + (((size_t)(b * 16 + h)) * 512 + qw + qq) * SK + s0 + lr;
        #pragma unroll
        for (int si = 0; si < 8; ++si){
          float v = accs[si][j] * 0.125f;
          if (HAS_BIAS && ((wb[si >> 1] >> ((si & 1) * 16 + lr)) & 1u)) v = -1e30f;
          const float p = __expf(v - mrow[j]) * rinv[j];
          awrow[si * 16] = p;
          sPw[qq * 128 + ((si * 2 + (lr >> 3)) ^ qq) * 8 + (lr & 7)] = f2bf(p);
        }
      }

      #pragma unroll
      for (int kt = 0; kt < 4; ++kt){
        bf16x8 pa = *(const bf16x8*)&sPw[lr * 128 + ((kt * 4 + lg) ^ lr) * 8];
        #pragma unroll
        for (int ni = 0; ni < 4; ++ni){
          bf16x8 vf = *(const bf16x8*)&Vb[(size_t)(ni * 16 + lr) * SK + s0 + kt * 32 + lg * 8];
          acco[ni] = __builtin_amdgcn_mfma_f32_16x16x32_bf16(pa, vf, acco[ni], 0, 0, 0);
        }
      }
    }
  } else {
    // ---------------- single-pass online flash ----------------
    for (int tt = 0; tt < NT; ++tt){
      const int s0 = tt * 128;
      __syncthreads();
      g2l16(Ksrc + (size_t)s0 * 1024, sKd);
      g2l16(Ksrc + (size_t)(s0 + 8) * 1024, sKd + 512);
      __syncthreads();

      f32x4 accs[8];
      #pragma unroll
      for (int si = 0; si < 8; ++si){
        f32x4 a = {};
        #pragma unroll
        for (int dt = 0; dt < 2; ++dt){
          bf16x8 kf = *(const bf16x8*)&sK[(si * 16 + lr) * 64 + ((dt * 4 + lg) ^ (lr & 7)) * 8];
          a = __builtin_amdgcn_mfma_f32_16x16x32_bf16(qf[dt], kf, a, 0, 0, 0);
        }
        accs[si] = a;
      }

      #pragma unroll
      for (int j = 0; j < 4; ++j){
        unsigned wb[4];
        if (HAS_BIAS){
          #pragma unroll
          for (int sp = 0; sp < 4; ++sp) wb[sp] = bitrow[j][tt * 4 + sp];
        }
        const int qq = lg * 4 + j;
        float vals[8];
        #pragma unroll
        for (int si = 0; si < 8; ++si){
          float v = accs[si][j] * 0.125f;
          if (HAS_BIAS && ((wb[si >> 1] >> ((si & 1) * 16 + lr)) & 1u)) v = -1e30f;
          vals[si] = v;
        }
        float tmax = vals[0];
        #pragma unroll
        for (int si = 1; si < 8; ++si) tmax = fmaxf(tmax, vals[si]);
        #pragma unroll
        for (int d = 1; d < 16; d <<= 1) tmax = fmaxf(tmax, __shfl_xor(tmax, d));
        const float mn = fmaxf(mrow[j], tmax);
        const float alpha = __expf(mrow[j] - mn);
        float ls = 0.f;
        #pragma unroll
        for (int si = 0; si < 8; ++si){
          const float p = __expf(vals[si] - mn);
          ls += p;
          sPw[qq * 128 + ((si * 2 + (lr >> 3)) ^ qq) * 8 + (lr & 7)] = f2bf(p);
        }
        lrow[j] = lrow[j] * alpha + ls;
        #pragma unroll
        for (int ni = 0; ni < 4; ++ni) acco[ni][j] *= alpha;
        mrow[j] = mn;
      }

      #pragma unroll
      for (int kt = 0; kt < 4; ++kt){
        bf16x8 pa = *(const bf16x8*)&sPw[lr * 128 + ((kt * 4 + lg) ^ lr) * 8];
        #pragma unroll
        for (int ni = 0; ni < 4; ++ni){
          bf16x8 vf = *(const bf16x8*)&Vb[(size_t)(ni * 16 + lr) * SK + s0 + kt * 32 + lg * 8];
          acco[ni] = __builtin_amdgcn_mfma_f32_16x16x32_bf16(pa, vf, acco[ni], 0, 0, 0);
        }
      }
    }

    #pragma unroll
    for (int j = 0; j < 4; ++j){
      #pragma unroll
      for (int d = 1; d < 16; d <<= 1) lrow[j] += __shfl_xor(lrow[j], d);
      const float r = 1.0f / lrow[j];
      #pragma unroll
      for (int ni = 0; ni < 4; ++ni) acco[ni][j] *= r;
    }
  }

  // epilogue
  #pragma unroll
  for (int ni = 0; ni < 4; ++ni)
    #pragma unroll
    for (int j = 0; j < 4; ++j){
      const size_t addr = ((size_t)(b * 512 + qw + lg * 4 + j)) * 1024 + h * 64 + ni * 16 + lr;
      const float v = acco[ni][j];
      if (MODE == 0)      scores[addr] = v;
      else if (MODE == 1) scores[addr] += 0.5f * v;
      else                concat[addr] = f2bf(scores[addr] + 0.5f * v);
    }
}

// ---------------------------------------------------------------------------
extern "C" void kernel_launch(void* const* d_in, const int* in_sizes, int n_in,
                              void* d_out, int out_size, void* d_ws, size_t ws_size,
                              hipStream_t stream){
  const float* q    = (const float*)d_in[0];
  const float* k_e  = (const float*)d_in[1];
  const float* v_e  = (const float*)d_in[2];
  const float* k_i  = (const float*)d_in[3];
  const float* v_i  = (const float*)d_in[4];
  const float* k_ei = (const float*)d_in[5];
  const float* v_ei = (const float*)d_in[6];
  const int* mask_e  = (const int*)d_in[7];
  const int* mask_ei = (const int*)d_in[8];
  const int* pad_e   = (const int*)d_in[9];
  const int* pad_ei  = (const int*)d_in[10];
  const float* Wq   = (const float*)d_in[11]; const float* bq   = (const float*)d_in[12];
  const float* Wke  = (const float*)d_in[13]; const float* bke  = (const float*)d_in[14];
  const float* Wve  = (const float*)d_in[15]; const float* bve  = (const float*)d_in[16];
  const float* Wki  = (const float*)d_in[17]; const float* bki  = (const float*)d_in[18];
  const float* Wvi  = (const float*)d_in[19]; const float* bvi  = (const float*)d_in[20];
  const float* Wkei = (const float*)d_in[21]; const float* bkei = (const float*)d_in[22];
  const float* Wvei = (const float*)d_in[23]; const float* bvei = (const float*)d_in[24];
  const float* Wout = (const float*)d_in[25]; const float* bout = (const float*)d_in[26];

  char* ws = (char*)d_ws;
  short* PW     = (short*)(ws);                 // 16 MB: 8 packed weights (bf16)
  short* Abf    = (short*)(ws + 16777216);      // 24 MB: bf16 staging; later bitmasks
  short* Qp     = (short*)(ws + 41943040);      // 8192x1024 bf16
  short* Kep    = (short*)(ws + 58720256);      // 8192x1024 bf16
  short* Kip    = (short*)(ws + 75497472);      // 4096x1024 bf16
  short* Keip   = (short*)(ws + 83886080);      // 12288x1024 bf16
  short* Vte    = (short*)(ws + 109051904);     // (16,16,64,512) bf16
  short* Vti    = (short*)(ws + 125829120);     // (16,16,64,256) bf16
  short* Vtei   = (short*)(ws + 134217728);     // (16,16,64,768) bf16
  float* scores = (float*)(ws + 159383552);     // 8192x1024 f32
  short* concat = (short*)(ws + 192937984);     // 8192x1024 bf16

  unsigned* bits_e  = (unsigned*)(ws + 16777216);            // 2 MB (reuses Abf)
  unsigned* bits_ei = (unsigned*)(ws + 16777216 + 2097152);  // 3 MB

  float* out0 = (float*)d_out;
  float* aw_e = out0 + 8388608;
  float* aw_i = out0 + 75497472;

  W8 w8;
  w8.w[0] = Wq;  w8.w[1] = Wke;  w8.w[2] = Wve;  w8.w[3] = Wki;
  w8.w[4] = Wvi; w8.w[5] = Wkei; w8.w[6] = Wvei; w8.w[7] = Wout;
  pack_w8<<<dim3(256, 8), 256, 0, stream>>>(w8, PW);

  // q
  cvt_bf16<<<4096, 256, 0, stream>>>(q, Abf, 1048576);
  gemm256<0><<<dim3(64, 4), 512, 0, stream>>>(Abf, PW + 0 * 1048576, bq, Qp, 512);
  // k_e
  cvt_bf16<<<4096, 256, 0, stream>>>(k_e, Abf, 1048576);
  gemm256<0><<<dim3(64, 4), 512, 0, stream>>>(Abf, PW + 1 * 1048576, bke, Kep, 512);
  // v_e
  cvt_bf16<<<4096, 256, 0, stream>>>(v_e, Abf, 1048576);
  gemm256<1><<<dim3(64, 4), 512, 0, stream>>>(Abf, PW + 2 * 1048576, bve, Vte, 512);
  // k_i
  cvt_bf16<<<2048, 256, 0, stream>>>(k_i, Abf, 524288);
  gemm256<0><<<dim3(32, 4), 512, 0, stream>>>(Abf, PW + 3 * 1048576, bki, Kip, 256);
  // v_i
  cvt_bf16<<<2048, 256, 0, stream>>>(v_i, Abf, 524288);
  gemm256<1><<<dim3(32, 4), 512, 0, stream>>>(Abf, PW + 4 * 1048576, bvi, Vti, 256);
  // k_ei
  cvt_bf16<<<6144, 256, 0, stream>>>(k_ei, Abf, 1572864);
  gemm256<0><<<dim3(96, 4), 512, 0, stream>>>(Abf, PW + 5 * 1048576, bkei, Keip, 768);
  // v_ei
  cvt_bf16<<<6144, 256, 0, stream>>>(v_ei, Abf, 1572864);
  gemm256<1><<<dim3(96, 4), 512, 0, stream>>>(Abf, PW + 6 * 1048576, bvei, Vtei, 768);

  // bitmasks (Abf region is free now)
  make_bits<<<dim3(2, 8192), 256, 0, stream>>>(mask_e,  pad_e,  bits_e,  512);
  make_bits<<<dim3(3, 8192), 256, 0, stream>>>(mask_ei, pad_ei, bits_ei, 768);

  attn3<512, true , 0><<<1024, 512, 0, stream>>>(Qp, Kep,  Vte,  bits_e,  aw_e, scores, nullptr);
  attn3<256, false, 1><<<1024, 512, 0, stream>>>(Qp, Kip,  Vti,  nullptr, aw_i, scores, nullptr);
  attn3<768, true , 2><<<1024, 512, 0, stream>>>(Qp, Keip, Vtei, bits_ei, nullptr, scores, concat);

  gemm256<2><<<dim3(64, 4), 512, 0, stream>>>(concat, PW + 7 * 1048576, bout, out0, 512);
}

// Round 6
// 699.124 us; speedup vs baseline: 1.2584x; 1.2584x over previous
//
#include <hip/hip_runtime.h>
#include <stdint.h>

typedef __attribute__((ext_vector_type(8))) short bf16x8;
typedef __attribute__((ext_vector_type(4))) short s16x4;
typedef __attribute__((ext_vector_type(4))) float f32x4;

__device__ __forceinline__ short f2bf(float f){
  unsigned x = __float_as_uint(f);
  unsigned r = (x + 0x7fffu + ((x >> 16) & 1u)) >> 16;
  return (short)r;
}

// async global->LDS, 16B per lane (dest = wave-uniform base + lane*16)
__device__ __forceinline__ void g2l16(const void* g, void* l){
  __builtin_amdgcn_global_load_lds(
      (const __attribute__((address_space(1))) unsigned int*)(unsigned long long)(uintptr_t)g,
      (__attribute__((address_space(3))) unsigned int*)(unsigned int)(uintptr_t)l,
      16, 0, 0);
}

// ---------------------------------------------------------------------------
// f32 -> bf16 convert, 8 elems/thread
// ---------------------------------------------------------------------------
__global__ __launch_bounds__(256) void cvt_bf16(const float* __restrict__ in,
                                                short* __restrict__ out, int n8){
  const int i = blockIdx.x * 256 + threadIdx.x;
  if (i >= n8) return;
  const float4* p = (const float4*)in + (size_t)i * 2;
  const float4 a = p[0], b = p[1];
  bf16x8 v;
  v[0] = f2bf(a.x); v[1] = f2bf(a.y); v[2] = f2bf(a.z); v[3] = f2bf(a.w);
  v[4] = f2bf(b.x); v[5] = f2bf(b.y); v[6] = f2bf(b.z); v[7] = f2bf(b.w);
  *(bf16x8*)(out + (size_t)i * 8) = v;
}

// ---------------------------------------------------------------------------
// (mask || pad) -> bitmask. grid: (SK/256, B*SQ). 1 bit per (row, s).
// ---------------------------------------------------------------------------
__global__ __launch_bounds__(256)
void make_bits(const int* __restrict__ mask, const int* __restrict__ pad,
               unsigned* __restrict__ bits, int SK){
  const int s = blockIdx.x * 256 + threadIdx.x;
  const size_t row = blockIdx.y;               // b*512 + q
  const int b = (int)(row >> 9);
  const bool v = (mask[row * SK + s] != 0) || (pad[(size_t)b * SK + s] != 0);
  unsigned long long bal = __ballot(v);
  const int lane = threadIdx.x & 63;
  if ((lane & 31) == 0)
    bits[(row * SK + s) >> 5] = (unsigned)(bal >> (lane & 32));
}

// ---------------------------------------------------------------------------
// Pack 8 weights (f32, 1024x1024 row-major K x N) into bf16 tiles:
// packed[(nt*32+kt)*4096 + nl*32 + kl] = W[(kt*32+kl)*1024 + nt*128 + nl]
// grid: (256 tiles, 8 weights)
// ---------------------------------------------------------------------------
struct W8 { const float* w[8]; };
__global__ __launch_bounds__(256) void pack_w8(W8 ws8, short* __restrict__ out){
  const int m = blockIdx.y;
  const float* __restrict__ W = ws8.w[m];
  short* o = out + (size_t)m * 1048576 + (size_t)blockIdx.x * 4096;
  const int kt = blockIdx.x & 31, nt = blockIdx.x >> 5;
  const int t = threadIdx.x;
  #pragma unroll
  for (int i = 0; i < 16; ++i){
    int flat = i * 256 + t;              // 0..4095
    int kl = flat >> 7;                  // /128
    int nl = flat & 127;
    o[nl * 32 + kl] = f2bf(W[(size_t)(kt * 32 + kl) * 1024 + nt * 128 + nl]);
  }
}

// ---------------------------------------------------------------------------
// GEMM: C(M,1024) = A(M,1024)bf16 @ Wp + bias(f32).  128x128 tile, BK=32.
// OM=0: C bf16 row-major. OM=1: C bf16 as (B,H=16,DK=64,S). OM=2: C f32.
// ---------------------------------------------------------------------------
template<int OM>
__global__ __launch_bounds__(256)
void gemm128(const short* __restrict__ A, const short* __restrict__ Wp,
             const float* __restrict__ bias, void* __restrict__ Cv, int S){
  __shared__ short sA[128 * 32];
  __shared__ short sB[128 * 32];
  const int t = threadIdx.x;
  const int m0 = blockIdx.x * 128;
  const int nt = blockIdx.y;             // 0..7
  const int n0 = nt * 128;
  const int w = t >> 6, lane = t & 63, lr = lane & 15, lg = lane >> 4;
  const int wm = (w >> 1) * 64, wn = (w & 1) * 64;

  const int arow  = t >> 2;
  const int acol8 = (t & 3) * 8;
  const short* Ag = A + (size_t)(m0 + arow) * 1024 + acol8;
  const short* Bg = Wp + (size_t)nt * 32 * 4096 + t * 8;
  short* sAp = sA + t * 8;
  short* sBp = sB + t * 8;

  f32x4 acc[4][4] = {};

  for (int kt = 0; kt < 32; ++kt){
    __syncthreads();
    g2l16(Ag + kt * 32, sAp);
    g2l16(Ag + 64 * 1024 + kt * 32, sAp + 64 * 32);
    const short* bt = Bg + (size_t)kt * 4096;
    g2l16(bt, sBp);
    g2l16(bt + 2048, sBp + 2048);
    __syncthreads();

    bf16x8 af[4], bfr[4];
    #pragma unroll
    for (int mi = 0; mi < 4; ++mi)
      af[mi] = *(const bf16x8*)&sA[(wm + mi * 16 + lr) * 32 + lg * 8];
    #pragma unroll
    for (int ni = 0; ni < 4; ++ni)
      bfr[ni] = *(const bf16x8*)&sB[(wn + ni * 16 + lr) * 32 + lg * 8];
    #pragma unroll
    for (int mi = 0; mi < 4; ++mi)
      #pragma unroll
      for (int ni = 0; ni < 4; ++ni)
        acc[mi][ni] = __builtin_amdgcn_mfma_f32_16x16x32_bf16(
            af[mi], bfr[ni], acc[mi][ni], 0, 0, 0);
  }

  #pragma unroll
  for (int ni = 0; ni < 4; ++ni){
    const int n = n0 + wn + ni * 16 + lr;
    const float bv = bias[n];
    #pragma unroll
    for (int mi = 0; mi < 4; ++mi){
      const int mb = m0 + wm + mi * 16 + lg * 4;
      if (OM == 0){
        short* C = (short*)Cv;
        #pragma unroll
        for (int j = 0; j < 4; ++j)
          C[(size_t)(mb + j) * 1024 + n] = f2bf(acc[mi][ni][j] + bv);
      } else if (OM == 1){
        short* C = (short*)Cv;
        const int bb = mb / S, sb = mb % S;
        const int hh = n >> 6, dk = n & 63;
        s16x4 pk;
        #pragma unroll
        for (int j = 0; j < 4; ++j) pk[j] = f2bf(acc[mi][ni][j] + bv);
        *(s16x4*)&C[(((size_t)bb * 16 + hh) * 64 + dk) * S + sb] = pk;
      } else {
        float* C = (float*)Cv;
        #pragma unroll
        for (int j = 0; j < 4; ++j)
          C[(size_t)(mb + j) * 1024 + n] = acc[mi][ni][j] + bv;
      }
    }
  }
}

// ---------------------------------------------------------------------------
// Flash attention. Block = (b, h, 64 q-rows), 4 waves (16 q each).
// MODE 0/1 (needs aw): two-phase — P1 stats (m,l), P2 recompute + aw + PV.
// MODE 2 (no aw): single-pass online-rescale flash (V still LDS-staged).
// K staged via global_load_lds, XOR-swizzled. P bounced through per-wave LDS.
// MODE: 0 scores = o ; 1 scores += 0.5*o ; 2 concat = bf16(scores + 0.5*o)
// ---------------------------------------------------------------------------
template<int SK, bool HAS_BIAS, int MODE>
__global__ __launch_bounds__(256)
void attn2(const short* __restrict__ Qp, const short* __restrict__ Kp,
           const short* __restrict__ Vt, const unsigned* __restrict__ bits,
           float* __restrict__ aw, float* __restrict__ scores,
           short* __restrict__ concat){
  constexpr int NT  = SK / 128;
  constexpr int SKW = SK / 32;
  __shared__ short sK[8192];   // [128 s][8 chunks], pos c holds g=c^(s&7)
  __shared__ short sV[8192];   // [64 d][16 chunks], pos c holds g=c^(d&15)
  __shared__ short sP[8192];   // per-wave [16 q][16 chunks], pos c holds g=c^q

  const int bid = blockIdx.x;
  const int qt = bid & 7, h = (bid >> 3) & 15, b = bid >> 7;
  const int q0 = qt * 64;
  const int t = threadIdx.x, w = t >> 6, lane = t & 63;
  const int lr = lane & 15, lg = lane >> 4;
  const int qw = q0 + w * 16;

  // Q fragments
  const short* Qb = Qp + ((size_t)(b * 512 + qw + lr)) * 1024 + h * 64;
  bf16x8 qf[2];
  qf[0] = *(const bf16x8*)&Qb[lg * 8];
  qf[1] = *(const bf16x8*)&Qb[32 + lg * 8];

  const int kchunk = (lane & 7) ^ ((lane >> 3) & 7);
  const short* Ksrc = Kp + ((size_t)b * SK + w * 32 + (lane >> 3)) * 1024 + h * 64 + kchunk * 8;
  short* sKd = sK + w * 2048 + lane * 8;
  short* sVd = sV + w * 2048 + lane * 8;
  const short* Vsrc = Vt + ((size_t)(b * 16 + h)) * 64 * SK;
  short* sPw = sP + w * 2048;

  const unsigned* bitrow[4];
  if (HAS_BIAS){
    #pragma unroll
    for (int j = 0; j < 4; ++j)
      bitrow[j] = bits + ((size_t)(b * 512 + qw + lg * 4 + j)) * SKW;
  }

  float mrow[4], lrow[4];
  #pragma unroll
  for (int j = 0; j < 4; ++j){ mrow[j] = -3.4e38f; lrow[j] = 0.f; }
  f32x4 acco[4] = {};

  if (MODE != 2){
    // ---------------- Phase 1: stats ----------------
    for (int tt = 0; tt < NT; ++tt){
      const int s0 = tt * 128;
      __syncthreads();
      #pragma unroll
      for (int i = 0; i < 4; ++i)
        g2l16(Ksrc + ((size_t)s0 + i * 8) * 1024, sKd + i * 512);
      __syncthreads();

      f32x4 accs[8];
      #pragma unroll
      for (int si = 0; si < 8; ++si){
        f32x4 a = {};
        #pragma unroll
        for (int dt = 0; dt < 2; ++dt){
          bf16x8 kf = *(const bf16x8*)&sK[(si * 16 + lr) * 64 + ((dt * 4 + lg) ^ (lr & 7)) * 8];
          a = __builtin_amdgcn_mfma_f32_16x16x32_bf16(qf[dt], kf, a, 0, 0, 0);
        }
        accs[si] = a;
      }

      #pragma unroll
      for (int j = 0; j < 4; ++j){
        unsigned wb[4];
        if (HAS_BIAS){
          #pragma unroll
          for (int sp = 0; sp < 4; ++sp) wb[sp] = bitrow[j][(s0 >> 5) + sp];
        }
        float vals[8];
        #pragma unroll
        for (int si = 0; si < 8; ++si){
          float v = accs[si][j] * 0.125f;
          if (HAS_BIAS && ((wb[si >> 1] >> ((si & 1) * 16 + lr)) & 1u)) v = -1e30f;
          vals[si] = v;
        }
        float mt = vals[0];
        #pragma unroll
        for (int si = 1; si < 8; ++si) mt = fmaxf(mt, vals[si]);
        const float mn = fmaxf(mrow[j], mt);
        float ssum = 0.f;
        #pragma unroll
        for (int si = 0; si < 8; ++si) ssum += __expf(vals[si] - mn);
        lrow[j] = lrow[j] * __expf(mrow[j] - mn) + ssum;
        mrow[j] = mn;
      }
    }

    // merge (m,l) across the 16 lr lanes
    #pragma unroll
    for (int j = 0; j < 4; ++j){
      #pragma unroll
      for (int d = 1; d < 16; d <<= 1){
        float mo = __shfl_xor(mrow[j], d);
        float lo = __shfl_xor(lrow[j], d);
        float mn = fmaxf(mrow[j], mo);
        lrow[j] = lrow[j] * __expf(mrow[j] - mn) + lo * __expf(mo - mn);
        mrow[j] = mn;
      }
    }
    float rinv[4];
    #pragma unroll
    for (int j = 0; j < 4; ++j) rinv[j] = 1.0f / lrow[j];

    // ---------------- Phase 2: aw + PV ----------------
    for (int tt = 0; tt < NT; ++tt){
      const int s0 = tt * 128;
      __syncthreads();
      #pragma unroll
      for (int i = 0; i < 4; ++i)
        g2l16(Ksrc + ((size_t)s0 + i * 8) * 1024, sKd + i * 512);
      #pragma unroll
      for (int i = 0; i < 4; ++i){
        const int dd = w * 16 + i * 4 + (lane >> 4);
        const int cg = (lane & 15) ^ ((i * 4 + (lane >> 4)) & 15);
        g2l16(Vsrc + (size_t)dd * SK + s0 + cg * 8, sVd + i * 512);
      }
      __syncthreads();

      f32x4 accs[8];
      #pragma unroll
      for (int si = 0; si < 8; ++si){
        f32x4 a = {};
        #pragma unroll
        for (int dt = 0; dt < 2; ++dt){
          bf16x8 kf = *(const bf16x8*)&sK[(si * 16 + lr) * 64 + ((dt * 4 + lg) ^ (lr & 7)) * 8];
          a = __builtin_amdgcn_mfma_f32_16x16x32_bf16(qf[dt], kf, a, 0, 0, 0);
        }
        accs[si] = a;
      }

      #pragma unroll
      for (int j = 0; j < 4; ++j){
        unsigned wb[4];
        if (HAS_BIAS){
          #pragma unroll
          for (int sp = 0; sp < 4; ++sp) wb[sp] = bitrow[j][(s0 >> 5) + sp];
        }
        const int qq = lg * 4 + j;
        float* awrow = aw + (((size_t)(b * 16 + h)) * 512 + qw + qq) * SK + s0 + lr;
        #pragma unroll
        for (int si = 0; si < 8; ++si){
          float v = accs[si][j] * 0.125f;
          if (HAS_BIAS && ((wb[si >> 1] >> ((si & 1) * 16 + lr)) & 1u)) v = -1e30f;
          const float p = __expf(v - mrow[j]) * rinv[j];
          awrow[si * 16] = p;
          sPw[qq * 128 + ((si * 2 + (lr >> 3)) ^ qq) * 8 + (lr & 7)] = f2bf(p);
        }
      }

      // PV (same-wave LDS write->read; DS ops are in-order)
      #pragma unroll
      for (int kt = 0; kt < 4; ++kt){
        bf16x8 pa = *(const bf16x8*)&sPw[lr * 128 + ((kt * 4 + lg) ^ lr) * 8];
        #pragma unroll
        for (int ni = 0; ni < 4; ++ni){
          bf16x8 vf = *(const bf16x8*)&sV[(ni * 16 + lr) * 128 + ((kt * 4 + lg) ^ lr) * 8];
          acco[ni] = __builtin_amdgcn_mfma_f32_16x16x32_bf16(pa, vf, acco[ni], 0, 0, 0);
        }
      }
    }
  } else {
    // ---------------- single-pass online flash (no aw) ----------------
    for (int tt = 0; tt < NT; ++tt){
      const int s0 = tt * 128;
      __syncthreads();
      #pragma unroll
      for (int i = 0; i < 4; ++i)
        g2l16(Ksrc + ((size_t)s0 + i * 8) * 1024, sKd + i * 512);
      #pragma unroll
      for (int i = 0; i < 4; ++i){
        const int dd = w * 16 + i * 4 + (lane >> 4);
        const int cg = (lane & 15) ^ ((i * 4 + (lane >> 4)) & 15);
        g2l16(Vsrc + (size_t)dd * SK + s0 + cg * 8, sVd + i * 512);
      }
      __syncthreads();

      f32x4 accs[8];
      #pragma unroll
      for (int si = 0; si < 8; ++si){
        f32x4 a = {};
        #pragma unroll
        for (int dt = 0; dt < 2; ++dt){
          bf16x8 kf = *(const bf16x8*)&sK[(si * 16 + lr) * 64 + ((dt * 4 + lg) ^ (lr & 7)) * 8];
          a = __builtin_amdgcn_mfma_f32_16x16x32_bf16(qf[dt], kf, a, 0, 0, 0);
        }
        accs[si] = a;
      }

      #pragma unroll
      for (int j = 0; j < 4; ++j){
        unsigned wb[4];
        if (HAS_BIAS){
          #pragma unroll
          for (int sp = 0; sp < 4; ++sp) wb[sp] = bitrow[j][(s0 >> 5) + sp];
        }
        const int qq = lg * 4 + j;
        float vals[8];
        #pragma unroll
        for (int si = 0; si < 8; ++si){
          float v = accs[si][j] * 0.125f;
          if (HAS_BIAS && ((wb[si >> 1] >> ((si & 1) * 16 + lr)) & 1u)) v = -1e30f;
          vals[si] = v;
        }
        float tmax = vals[0];
        #pragma unroll
        for (int si = 1; si < 8; ++si) tmax = fmaxf(tmax, vals[si]);
        #pragma unroll
        for (int d = 1; d < 16; d <<= 1) tmax = fmaxf(tmax, __shfl_xor(tmax, d));
        const float mn = fmaxf(mrow[j], tmax);
        const float alpha = __expf(mrow[j] - mn);
        float ls = 0.f;
        #pragma unroll
        for (int si = 0; si < 8; ++si){
          const float p = __expf(vals[si] - mn);
          ls += p;
          sPw[qq * 128 + ((si * 2 + (lr >> 3)) ^ qq) * 8 + (lr & 7)] = f2bf(p);
        }
        lrow[j] = lrow[j] * alpha + ls;
        #pragma unroll
        for (int ni = 0; ni < 4; ++ni) acco[ni][j] *= alpha;
        mrow[j] = mn;
      }

      #pragma unroll
      for (int kt = 0; kt < 4; ++kt){
        bf16x8 pa = *(const bf16x8*)&sPw[lr * 128 + ((kt * 4 + lg) ^ lr) * 8];
        #pragma unroll
        for (int ni = 0; ni < 4; ++ni){
          bf16x8 vf = *(const bf16x8*)&sV[(ni * 16 + lr) * 128 + ((kt * 4 + lg) ^ lr) * 8];
          acco[ni] = __builtin_amdgcn_mfma_f32_16x16x32_bf16(pa, vf, acco[ni], 0, 0, 0);
        }
      }
    }

    // final normalize: l is partial per-lane (m already uniform) -> sum
    #pragma unroll
    for (int j = 0; j < 4; ++j){
      #pragma unroll
      for (int d = 1; d < 16; d <<= 1) lrow[j] += __shfl_xor(lrow[j], d);
      const float r = 1.0f / lrow[j];
      #pragma unroll
      for (int ni = 0; ni < 4; ++ni) acco[ni][j] *= r;
    }
  }

  // epilogue: combine into scores / concat
  #pragma unroll
  for (int ni = 0; ni < 4; ++ni)
    #pragma unroll
    for (int j = 0; j < 4; ++j){
      const size_t addr = ((size_t)(b * 512 + qw + lg * 4 + j)) * 1024 + h * 64 + ni * 16 + lr;
      const float v = acco[ni][j];
      if (MODE == 0)      scores[addr] = v;
      else if (MODE == 1) scores[addr] += 0.5f * v;
      else                concat[addr] = f2bf(scores[addr] + 0.5f * v);
    }
}

// ---------------------------------------------------------------------------
extern "C" void kernel_launch(void* const* d_in, const int* in_sizes, int n_in,
                              void* d_out, int out_size, void* d_ws, size_t ws_size,
                              hipStream_t stream){
  const float* q    = (const float*)d_in[0];
  const float* k_e  = (const float*)d_in[1];
  const float* v_e  = (const float*)d_in[2];
  const float* k_i  = (const float*)d_in[3];
  const float* v_i  = (const float*)d_in[4];
  const float* k_ei = (const float*)d_in[5];
  const float* v_ei = (const float*)d_in[6];
  const int* mask_e  = (const int*)d_in[7];
  const int* mask_ei = (const int*)d_in[8];
  const int* pad_e   = (const int*)d_in[9];
  const int* pad_ei  = (const int*)d_in[10];
  const float* Wq   = (const float*)d_in[11]; const float* bq   = (const float*)d_in[12];
  const float* Wke  = (const float*)d_in[13]; const float* bke  = (const float*)d_in[14];
  const float* Wve  = (const float*)d_in[15]; const float* bve  = (const float*)d_in[16];
  const float* Wki  = (const float*)d_in[17]; const float* bki  = (const float*)d_in[18];
  const float* Wvi  = (const float*)d_in[19]; const float* bvi  = (const float*)d_in[20];
  const float* Wkei = (const float*)d_in[21]; const float* bkei = (const float*)d_in[22];
  const float* Wvei = (const float*)d_in[23]; const float* bvei = (const float*)d_in[24];
  const float* Wout = (const float*)d_in[25]; const float* bout = (const float*)d_in[26];

  char* ws = (char*)d_ws;
  short* PW     = (short*)(ws);                 // 16 MB: 8 packed weights (bf16)
  short* Abf    = (short*)(ws + 16777216);      // 24 MB: bf16 staging; later bitmasks
  short* Qp     = (short*)(ws + 41943040);      // 8192x1024 bf16
  short* Kep    = (short*)(ws + 58720256);      // 8192x1024 bf16
  short* Kip    = (short*)(ws + 75497472);      // 4096x1024 bf16
  short* Keip   = (short*)(ws + 83886080);      // 12288x1024 bf16
  short* Vte    = (short*)(ws + 109051904);     // (16,16,64,512) bf16
  short* Vti    = (short*)(ws + 125829120);     // (16,16,64,256) bf16
  short* Vtei   = (short*)(ws + 134217728);     // (16,16,64,768) bf16
  float* scores = (float*)(ws + 159383552);     // 8192x1024 f32
  short* concat = (short*)(ws + 192937984);     // 8192x1024 bf16

  unsigned* bits_e  = (unsigned*)(ws + 16777216);            // 2 MB (reuses Abf)
  unsigned* bits_ei = (unsigned*)(ws + 16777216 + 2097152);  // 3 MB

  float* out0 = (float*)d_out;
  float* aw_e = out0 + 8388608;
  float* aw_i = out0 + 75497472;

  W8 w8;
  w8.w[0] = Wq;  w8.w[1] = Wke;  w8.w[2] = Wve;  w8.w[3] = Wki;
  w8.w[4] = Wvi; w8.w[5] = Wkei; w8.w[6] = Wvei; w8.w[7] = Wout;
  pack_w8<<<dim3(256, 8), 256, 0, stream>>>(w8, PW);

  // q
  cvt_bf16<<<4096, 256, 0, stream>>>(q, Abf, 1048576);
  gemm128<0><<<dim3(64, 8), 256, 0, stream>>>(Abf, PW + 0 * 1048576, bq, Qp, 512);
  // k_e
  cvt_bf16<<<4096, 256, 0, stream>>>(k_e, Abf, 1048576);
  gemm128<0><<<dim3(64, 8), 256, 0, stream>>>(Abf, PW + 1 * 1048576, bke, Kep, 512);
  // v_e
  cvt_bf16<<<4096, 256, 0, stream>>>(v_e, Abf, 1048576);
  gemm128<1><<<dim3(64, 8), 256, 0, stream>>>(Abf, PW + 2 * 1048576, bve, Vte, 512);
  // k_i
  cvt_bf16<<<2048, 256, 0, stream>>>(k_i, Abf, 524288);
  gemm128<0><<<dim3(32, 8), 256, 0, stream>>>(Abf, PW + 3 * 1048576, bki, Kip, 256);
  // v_i
  cvt_bf16<<<2048, 256, 0, stream>>>(v_i, Abf, 524288);
  gemm128<1><<<dim3(32, 8), 256, 0, stream>>>(Abf, PW + 4 * 1048576, bvi, Vti, 256);
  // k_ei
  cvt_bf16<<<6144, 256, 0, stream>>>(k_ei, Abf, 1572864);
  gemm128<0><<<dim3(96, 8), 256, 0, stream>>>(Abf, PW + 5 * 1048576, bkei, Keip, 768);
  // v_ei
  cvt_bf16<<<6144, 256, 0, stream>>>(v_ei, Abf, 1572864);
  gemm128<1><<<dim3(96, 8), 256, 0, stream>>>(Abf, PW + 6 * 1048576, bvei, Vtei, 768);

  // bitmasks (Abf region is free now)
  make_bits<<<dim3(2, 8192), 256, 0, stream>>>(mask_e,  pad_e,  bits_e,  512);
  make_bits<<<dim3(3, 8192), 256, 0, stream>>>(mask_ei, pad_ei, bits_ei, 768);

  attn2<512, true , 0><<<2048, 256, 0, stream>>>(Qp, Kep,  Vte,  bits_e,  aw_e, scores, nullptr);
  attn2<256, false, 1><<<2048, 256, 0, stream>>>(Qp, Kip,  Vti,  nullptr, aw_i, scores, nullptr);
  attn2<768, true , 2><<<2048, 256, 0, stream>>>(Qp, Keip, Vtei, bits_ei, nullptr, scores, concat);

  gemm128<2><<<dim3(64, 8), 256, 0, stream>>>(concat, PW + 7 * 1048576, bout, out0, 512);
}

// Round 7
// 661.365 us; speedup vs baseline: 1.3302x; 1.0571x over previous
//
#include <hip/hip_runtime.h>
#include <stdint.h>

typedef __attribute__((ext_vector_type(8))) short bf16x8;
typedef __attribute__((ext_vector_type(4))) short s16x4;
typedef __attribute__((ext_vector_type(4))) float f32x4;

__device__ __forceinline__ short f2bf(float f){
  unsigned x = __float_as_uint(f);
  unsigned r = (x + 0x7fffu + ((x >> 16) & 1u)) >> 16;
  return (short)r;
}

// async global->LDS, 16B per lane (dest = wave-uniform base + lane*16)
__device__ __forceinline__ void g2l16(const void* g, void* l){
  __builtin_amdgcn_global_load_lds(
      (const __attribute__((address_space(1))) unsigned int*)(unsigned long long)(uintptr_t)g,
      (__attribute__((address_space(3))) unsigned int*)(unsigned int)(uintptr_t)l,
      16, 0, 0);
}

// ---------------------------------------------------------------------------
// f32 -> bf16 convert, 8 elems/thread
// ---------------------------------------------------------------------------
__global__ __launch_bounds__(256) void cvt_bf16(const float* __restrict__ in,
                                                short* __restrict__ out, int n8){
  const int i = blockIdx.x * 256 + threadIdx.x;
  if (i >= n8) return;
  const float4* p = (const float4*)in + (size_t)i * 2;
  const float4 a = p[0], b = p[1];
  bf16x8 v;
  v[0] = f2bf(a.x); v[1] = f2bf(a.y); v[2] = f2bf(a.z); v[3] = f2bf(a.w);
  v[4] = f2bf(b.x); v[5] = f2bf(b.y); v[6] = f2bf(b.z); v[7] = f2bf(b.w);
  *(bf16x8*)(out + (size_t)i * 8) = v;
}

// ---------------------------------------------------------------------------
// (mask || pad) -> bitmask. grid: (SK/256, B*SQ). 1 bit per (row, s).
// ---------------------------------------------------------------------------
__global__ __launch_bounds__(256)
void make_bits(const int* __restrict__ mask, const int* __restrict__ pad,
               unsigned* __restrict__ bits, int SK){
  const int s = blockIdx.x * 256 + threadIdx.x;
  const size_t row = blockIdx.y;               // b*512 + q
  const int b = (int)(row >> 9);
  const bool v = (mask[row * SK + s] != 0) || (pad[(size_t)b * SK + s] != 0);
  unsigned long long bal = __ballot(v);
  const int lane = threadIdx.x & 63;
  if ((lane & 31) == 0)
    bits[(row * SK + s) >> 5] = (unsigned)(bal >> (lane & 32));
}

// ---------------------------------------------------------------------------
// Pack 8 weights (f32, 1024x1024 row-major K x N) into bf16 tiles:
// packed[(nt*32+kt)*4096 + nl*32 + kl] = W[(kt*32+kl)*1024 + nt*128 + nl]
// grid: (256 tiles, 8 weights)
// ---------------------------------------------------------------------------
struct W8 { const float* w[8]; };
__global__ __launch_bounds__(256) void pack_w8(W8 ws8, short* __restrict__ out){
  const int m = blockIdx.y;
  const float* __restrict__ W = ws8.w[m];
  short* o = out + (size_t)m * 1048576 + (size_t)blockIdx.x * 4096;
  const int kt = blockIdx.x & 31, nt = blockIdx.x >> 5;
  const int t = threadIdx.x;
  #pragma unroll
  for (int i = 0; i < 16; ++i){
    int flat = i * 256 + t;              // 0..4095
    int kl = flat >> 7;                  // /128
    int nl = flat & 127;
    o[nl * 32 + kl] = f2bf(W[(size_t)(kt * 32 + kl) * 1024 + nt * 128 + nl]);
  }
}

// ---------------------------------------------------------------------------
// GEMM: C(M,1024) = A(M,1024)bf16 @ Wp + bias(f32).  128x128 tile, BK=32.
// Double-buffered 2-phase K-loop: STAGE(kt+1) issued BEFORE compute(kt);
// one barrier per iteration -> load latency hides under MFMA.
// OM=0: C bf16 row-major. OM=1: C bf16 as (B,H=16,DK=64,S). OM=2: C f32.
// ---------------------------------------------------------------------------
template<int OM>
__global__ __launch_bounds__(256)
void gemm128(const short* __restrict__ A, const short* __restrict__ Wp,
             const float* __restrict__ bias, void* __restrict__ Cv, int S){
  __shared__ short sA[2][4096];
  __shared__ short sB[2][4096];
  const int t = threadIdx.x;
  const int m0 = blockIdx.x * 128;
  const int nt = blockIdx.y;             // 0..7
  const int n0 = nt * 128;
  const int w = t >> 6, lane = t & 63, lr = lane & 15, lg = lane >> 4;
  const int wm = (w >> 1) * 64, wn = (w & 1) * 64;

  const int arow  = t >> 2;
  const int acol8 = (t & 3) * 8;
  const short* Ag = A + (size_t)(m0 + arow) * 1024 + acol8;
  const short* Bg = Wp + (size_t)nt * 32 * 4096 + t * 8;

  f32x4 acc[4][4] = {};

  // prologue: stage tile 0 into buffer 0
  {
    g2l16(Ag, sA[0] + t * 8);
    g2l16(Ag + 64 * 1024, sA[0] + 2048 + t * 8);
    g2l16(Bg, sB[0] + t * 8);
    g2l16(Bg + 2048, sB[0] + 2048 + t * 8);
  }

  int cur = 0;
  for (int kt = 0; kt < 32; ++kt){
    __syncthreads();                     // drains vmcnt -> buf[cur] ready
    if (kt < 31){                        // issue next tile into buf[cur^1]
      const int kn = kt + 1;
      g2l16(Ag + kn * 32, sA[cur ^ 1] + t * 8);
      g2l16(Ag + 64 * 1024 + kn * 32, sA[cur ^ 1] + 2048 + t * 8);
      const short* bt = Bg + (size_t)kn * 4096;
      g2l16(bt, sB[cur ^ 1] + t * 8);
      g2l16(bt + 2048, sB[cur ^ 1] + 2048 + t * 8);
    }

    bf16x8 af[4], bfr[4];
    #pragma unroll
    for (int mi = 0; mi < 4; ++mi)
      af[mi] = *(const bf16x8*)&sA[cur][(wm + mi * 16 + lr) * 32 + lg * 8];
    #pragma unroll
    for (int ni = 0; ni < 4; ++ni)
      bfr[ni] = *(const bf16x8*)&sB[cur][(wn + ni * 16 + lr) * 32 + lg * 8];
    #pragma unroll
    for (int mi = 0; mi < 4; ++mi)
      #pragma unroll
      for (int ni = 0; ni < 4; ++ni)
        acc[mi][ni] = __builtin_amdgcn_mfma_f32_16x16x32_bf16(
            af[mi], bfr[ni], acc[mi][ni], 0, 0, 0);
    cur ^= 1;
  }

  #pragma unroll
  for (int ni = 0; ni < 4; ++ni){
    const int n = n0 + wn + ni * 16 + lr;
    const float bv = bias[n];
    #pragma unroll
    for (int mi = 0; mi < 4; ++mi){
      const int mb = m0 + wm + mi * 16 + lg * 4;
      if (OM == 0){
        short* C = (short*)Cv;
        #pragma unroll
        for (int j = 0; j < 4; ++j)
          C[(size_t)(mb + j) * 1024 + n] = f2bf(acc[mi][ni][j] + bv);
      } else if (OM == 1){
        short* C = (short*)Cv;
        const int bb = mb / S, sb = mb % S;
        const int hh = n >> 6, dk = n & 63;
        s16x4 pk;
        #pragma unroll
        for (int j = 0; j < 4; ++j) pk[j] = f2bf(acc[mi][ni][j] + bv);
        *(s16x4*)&C[(((size_t)bb * 16 + hh) * 64 + dk) * S + sb] = pk;
      } else {
        float* C = (float*)Cv;
        #pragma unroll
        for (int j = 0; j < 4; ++j)
          C[(size_t)(mb + j) * 1024 + n] = acc[mi][ni][j] + bv;
      }
    }
  }
}

// ---------------------------------------------------------------------------
// Flash attention. Block = (b, h, 64 q-rows), 4 waves (16 q each).
// MODE 0/1 (needs aw): two-phase — P1 stats (m,l), P2 recompute + aw + PV.
// MODE 2 (no aw): single-pass online-rescale flash (V still LDS-staged).
// K staged via global_load_lds, XOR-swizzled. P bounced through per-wave LDS.
// MODE: 0 scores = o ; 1 scores += 0.5*o ; 2 concat = bf16(scores + 0.5*o)
// ---------------------------------------------------------------------------
template<int SK, bool HAS_BIAS, int MODE>
__global__ __launch_bounds__(256)
void attn2(const short* __restrict__ Qp, const short* __restrict__ Kp,
           const short* __restrict__ Vt, const unsigned* __restrict__ bits,
           float* __restrict__ aw, float* __restrict__ scores,
           short* __restrict__ concat){
  constexpr int NT  = SK / 128;
  constexpr int SKW = SK / 32;
  __shared__ short sK[8192];   // [128 s][8 chunks], pos c holds g=c^(s&7)
  __shared__ short sV[8192];   // [64 d][16 chunks], pos c holds g=c^(d&15)
  __shared__ short sP[8192];   // per-wave [16 q][16 chunks], pos c holds g=c^q

  const int bid = blockIdx.x;
  const int qt = bid & 7, h = (bid >> 3) & 15, b = bid >> 7;
  const int q0 = qt * 64;
  const int t = threadIdx.x, w = t >> 6, lane = t & 63;
  const int lr = lane & 15, lg = lane >> 4;
  const int qw = q0 + w * 16;

  // Q fragments
  const short* Qb = Qp + ((size_t)(b * 512 + qw + lr)) * 1024 + h * 64;
  bf16x8 qf[2];
  qf[0] = *(const bf16x8*)&Qb[lg * 8];
  qf[1] = *(const bf16x8*)&Qb[32 + lg * 8];

  const int kchunk = (lane & 7) ^ ((lane >> 3) & 7);
  const short* Ksrc = Kp + ((size_t)b * SK + w * 32 + (lane >> 3)) * 1024 + h * 64 + kchunk * 8;
  short* sKd = sK + w * 2048 + lane * 8;
  short* sVd = sV + w * 2048 + lane * 8;
  const short* Vsrc = Vt + ((size_t)(b * 16 + h)) * 64 * SK;
  short* sPw = sP + w * 2048;

  const unsigned* bitrow[4];
  if (HAS_BIAS){
    #pragma unroll
    for (int j = 0; j < 4; ++j)
      bitrow[j] = bits + ((size_t)(b * 512 + qw + lg * 4 + j)) * SKW;
  }

  float mrow[4], lrow[4];
  #pragma unroll
  for (int j = 0; j < 4; ++j){ mrow[j] = -3.4e38f; lrow[j] = 0.f; }
  f32x4 acco[4] = {};

  if (MODE != 2){
    // ---------------- Phase 1: stats ----------------
    for (int tt = 0; tt < NT; ++tt){
      const int s0 = tt * 128;
      __syncthreads();
      #pragma unroll
      for (int i = 0; i < 4; ++i)
        g2l16(Ksrc + ((size_t)s0 + i * 8) * 1024, sKd + i * 512);
      __syncthreads();

      f32x4 accs[8];
      #pragma unroll
      for (int si = 0; si < 8; ++si){
        f32x4 a = {};
        #pragma unroll
        for (int dt = 0; dt < 2; ++dt){
          bf16x8 kf = *(const bf16x8*)&sK[(si * 16 + lr) * 64 + ((dt * 4 + lg) ^ (lr & 7)) * 8];
          a = __builtin_amdgcn_mfma_f32_16x16x32_bf16(qf[dt], kf, a, 0, 0, 0);
        }
        accs[si] = a;
      }

      #pragma unroll
      for (int j = 0; j < 4; ++j){
        unsigned wb[4];
        if (HAS_BIAS){
          #pragma unroll
          for (int sp = 0; sp < 4; ++sp) wb[sp] = bitrow[j][(s0 >> 5) + sp];
        }
        float vals[8];
        #pragma unroll
        for (int si = 0; si < 8; ++si){
          float v = accs[si][j] * 0.125f;
          if (HAS_BIAS && ((wb[si >> 1] >> ((si & 1) * 16 + lr)) & 1u)) v = -1e30f;
          vals[si] = v;
        }
        float mt = vals[0];
        #pragma unroll
        for (int si = 1; si < 8; ++si) mt = fmaxf(mt, vals[si]);
        const float mn = fmaxf(mrow[j], mt);
        float ssum = 0.f;
        #pragma unroll
        for (int si = 0; si < 8; ++si) ssum += __expf(vals[si] - mn);
        lrow[j] = lrow[j] * __expf(mrow[j] - mn) + ssum;
        mrow[j] = mn;
      }
    }

    // merge (m,l) across the 16 lr lanes
    #pragma unroll
    for (int j = 0; j < 4; ++j){
      #pragma unroll
      for (int d = 1; d < 16; d <<= 1){
        float mo = __shfl_xor(mrow[j], d);
        float lo = __shfl_xor(lrow[j], d);
        float mn = fmaxf(mrow[j], mo);
        lrow[j] = lrow[j] * __expf(mrow[j] - mn) + lo * __expf(mo - mn);
        mrow[j] = mn;
      }
    }
    float rinv[4];
    #pragma unroll
    for (int j = 0; j < 4; ++j) rinv[j] = 1.0f / lrow[j];

    // ---------------- Phase 2: aw + PV ----------------
    for (int tt = 0; tt < NT; ++tt){
      const int s0 = tt * 128;
      __syncthreads();
      #pragma unroll
      for (int i = 0; i < 4; ++i)
        g2l16(Ksrc + ((size_t)s0 + i * 8) * 1024, sKd + i * 512);
      #pragma unroll
      for (int i = 0; i < 4; ++i){
        const int dd = w * 16 + i * 4 + (lane >> 4);
        const int cg = (lane & 15) ^ ((i * 4 + (lane >> 4)) & 15);
        g2l16(Vsrc + (size_t)dd * SK + s0 + cg * 8, sVd + i * 512);
      }
      __syncthreads();

      f32x4 accs[8];
      #pragma unroll
      for (int si = 0; si < 8; ++si){
        f32x4 a = {};
        #pragma unroll
        for (int dt = 0; dt < 2; ++dt){
          bf16x8 kf = *(const bf16x8*)&sK[(si * 16 + lr) * 64 + ((dt * 4 + lg) ^ (lr & 7)) * 8];
          a = __builtin_amdgcn_mfma_f32_16x16x32_bf16(qf[dt], kf, a, 0, 0, 0);
        }
        accs[si] = a;
      }

      #pragma unroll
      for (int j = 0; j < 4; ++j){
        unsigned wb[4];
        if (HAS_BIAS){
          #pragma unroll
          for (int sp = 0; sp < 4; ++sp) wb[sp] = bitrow[j][(s0 >> 5) + sp];
        }
        const int qq = lg * 4 + j;
        float* awrow = aw + (((size_t)(b * 16 + h)) * 512 + qw + qq) * SK + s0 + lr;
        #pragma unroll
        for (int si = 0; si < 8; ++si){
          float v = accs[si][j] * 0.125f;
          if (HAS_BIAS && ((wb[si >> 1] >> ((si & 1) * 16 + lr)) & 1u)) v = -1e30f;
          const float p = __expf(v - mrow[j]) * rinv[j];
          awrow[si * 16] = p;
          sPw[qq * 128 + ((si * 2 + (lr >> 3)) ^ qq) * 8 + (lr & 7)] = f2bf(p);
        }
      }

      // PV (same-wave LDS write->read; DS ops are in-order)
      #pragma unroll
      for (int kt = 0; kt < 4; ++kt){
        bf16x8 pa = *(const bf16x8*)&sPw[lr * 128 + ((kt * 4 + lg) ^ lr) * 8];
        #pragma unroll
        for (int ni = 0; ni < 4; ++ni){
          bf16x8 vf = *(const bf16x8*)&sV[(ni * 16 + lr) * 128 + ((kt * 4 + lg) ^ lr) * 8];
          acco[ni] = __builtin_amdgcn_mfma_f32_16x16x32_bf16(pa, vf, acco[ni], 0, 0, 0);
        }
      }
    }
  } else {
    // ---------------- single-pass online flash (no aw) ----------------
    for (int tt = 0; tt < NT; ++tt){
      const int s0 = tt * 128;
      __syncthreads();
      #pragma unroll
      for (int i = 0; i < 4; ++i)
        g2l16(Ksrc + ((size_t)s0 + i * 8) * 1024, sKd + i * 512);
      #pragma unroll
      for (int i = 0; i < 4; ++i){
        const int dd = w * 16 + i * 4 + (lane >> 4);
        const int cg = (lane & 15) ^ ((i * 4 + (lane >> 4)) & 15);
        g2l16(Vsrc + (size_t)dd * SK + s0 + cg * 8, sVd + i * 512);
      }
      __syncthreads();

      f32x4 accs[8];
      #pragma unroll
      for (int si = 0; si < 8; ++si){
        f32x4 a = {};
        #pragma unroll
        for (int dt = 0; dt < 2; ++dt){
          bf16x8 kf = *(const bf16x8*)&sK[(si * 16 + lr) * 64 + ((dt * 4 + lg) ^ (lr & 7)) * 8];
          a = __builtin_amdgcn_mfma_f32_16x16x32_bf16(qf[dt], kf, a, 0, 0, 0);
        }
        accs[si] = a;
      }

      #pragma unroll
      for (int j = 0; j < 4; ++j){
        unsigned wb[4];
        if (HAS_BIAS){
          #pragma unroll
          for (int sp = 0; sp < 4; ++sp) wb[sp] = bitrow[j][(s0 >> 5) + sp];
        }
        const int qq = lg * 4 + j;
        float vals[8];
        #pragma unroll
        for (int si = 0; si < 8; ++si){
          float v = accs[si][j] * 0.125f;
          if (HAS_BIAS && ((wb[si >> 1] >> ((si & 1) * 16 + lr)) & 1u)) v = -1e30f;
          vals[si] = v;
        }
        float tmax = vals[0];
        #pragma unroll
        for (int si = 1; si < 8; ++si) tmax = fmaxf(tmax, vals[si]);
        #pragma unroll
        for (int d = 1; d < 16; d <<= 1) tmax = fmaxf(tmax, __shfl_xor(tmax, d));
        const float mn = fmaxf(mrow[j], tmax);
        const float alpha = __expf(mrow[j] - mn);
        float ls = 0.f;
        #pragma unroll
        for (int si = 0; si < 8; ++si){
          const float p = __expf(vals[si] - mn);
          ls += p;
          sPw[qq * 128 + ((si * 2 + (lr >> 3)) ^ qq) * 8 + (lr & 7)] = f2bf(p);
        }
        lrow[j] = lrow[j] * alpha + ls;
        #pragma unroll
        for (int ni = 0; ni < 4; ++ni) acco[ni][j] *= alpha;
        mrow[j] = mn;
      }

      #pragma unroll
      for (int kt = 0; kt < 4; ++kt){
        bf16x8 pa = *(const bf16x8*)&sPw[lr * 128 + ((kt * 4 + lg) ^ lr) * 8];
        #pragma unroll
        for (int ni = 0; ni < 4; ++ni){
          bf16x8 vf = *(const bf16x8*)&sV[(ni * 16 + lr) * 128 + ((kt * 4 + lg) ^ lr) * 8];
          acco[ni] = __builtin_amdgcn_mfma_f32_16x16x32_bf16(pa, vf, acco[ni], 0, 0, 0);
        }
      }
    }

    // final normalize: l is partial per-lane (m already uniform) -> sum
    #pragma unroll
    for (int j = 0; j < 4; ++j){
      #pragma unroll
      for (int d = 1; d < 16; d <<= 1) lrow[j] += __shfl_xor(lrow[j], d);
      const float r = 1.0f / lrow[j];
      #pragma unroll
      for (int ni = 0; ni < 4; ++ni) acco[ni][j] *= r;
    }
  }

  // epilogue: combine into scores / concat
  #pragma unroll
  for (int ni = 0; ni < 4; ++ni)
    #pragma unroll
    for (int j = 0; j < 4; ++j){
      const size_t addr = ((size_t)(b * 512 + qw + lg * 4 + j)) * 1024 + h * 64 + ni * 16 + lr;
      const float v = acco[ni][j];
      if (MODE == 0)      scores[addr] = v;
      else if (MODE == 1) scores[addr] += 0.5f * v;
      else                concat[addr] = f2bf(scores[addr] + 0.5f * v);
    }
}

// ---------------------------------------------------------------------------
extern "C" void kernel_launch(void* const* d_in, const int* in_sizes, int n_in,
                              void* d_out, int out_size, void* d_ws, size_t ws_size,
                              hipStream_t stream){
  const float* q    = (const float*)d_in[0];
  const float* k_e  = (const float*)d_in[1];
  const float* v_e  = (const float*)d_in[2];
  const float* k_i  = (const float*)d_in[3];
  const float* v_i  = (const float*)d_in[4];
  const float* k_ei = (const float*)d_in[5];
  const float* v_ei = (const float*)d_in[6];
  const int* mask_e  = (const int*)d_in[7];
  const int* mask_ei = (const int*)d_in[8];
  const int* pad_e   = (const int*)d_in[9];
  const int* pad_ei  = (const int*)d_in[10];
  const float* Wq   = (const float*)d_in[11]; const float* bq   = (const float*)d_in[12];
  const float* Wke  = (const float*)d_in[13]; const float* bke  = (const float*)d_in[14];
  const float* Wve  = (const float*)d_in[15]; const float* bve  = (const float*)d_in[16];
  const float* Wki  = (const float*)d_in[17]; const float* bki  = (const float*)d_in[18];
  const float* Wvi  = (const float*)d_in[19]; const float* bvi  = (const float*)d_in[20];
  const float* Wkei = (const float*)d_in[21]; const float* bkei = (const float*)d_in[22];
  const float* Wvei = (const float*)d_in[23]; const float* bvei = (const float*)d_in[24];
  const float* Wout = (const float*)d_in[25]; const float* bout = (const float*)d_in[26];

  char* ws = (char*)d_ws;
  short* PW     = (short*)(ws);                 // 16 MB: 8 packed weights (bf16)
  short* Abf    = (short*)(ws + 16777216);      // 24 MB: bf16 staging; later bitmasks
  short* Qp     = (short*)(ws + 41943040);      // 8192x1024 bf16
  short* Kep    = (short*)(ws + 58720256);      // 8192x1024 bf16
  short* Kip    = (short*)(ws + 75497472);      // 4096x1024 bf16
  short* Keip   = (short*)(ws + 83886080);      // 12288x1024 bf16
  short* Vte    = (short*)(ws + 109051904);     // (16,16,64,512) bf16
  short* Vti    = (short*)(ws + 125829120);     // (16,16,64,256) bf16
  short* Vtei   = (short*)(ws + 134217728);     // (16,16,64,768) bf16
  float* scores = (float*)(ws + 159383552);     // 8192x1024 f32
  short* concat = (short*)(ws + 192937984);     // 8192x1024 bf16

  unsigned* bits_e  = (unsigned*)(ws + 16777216);            // 2 MB (reuses Abf)
  unsigned* bits_ei = (unsigned*)(ws + 16777216 + 2097152);  // 3 MB

  float* out0 = (float*)d_out;
  float* aw_e = out0 + 8388608;
  float* aw_i = out0 + 75497472;

  W8 w8;
  w8.w[0] = Wq;  w8.w[1] = Wke;  w8.w[2] = Wve;  w8.w[3] = Wki;
  w8.w[4] = Wvi; w8.w[5] = Wkei; w8.w[6] = Wvei; w8.w[7] = Wout;
  pack_w8<<<dim3(256, 8), 256, 0, stream>>>(w8, PW);

  // q
  cvt_bf16<<<4096, 256, 0, stream>>>(q, Abf, 1048576);
  gemm128<0><<<dim3(64, 8), 256, 0, stream>>>(Abf, PW + 0 * 1048576, bq, Qp, 512);
  // k_e
  cvt_bf16<<<4096, 256, 0, stream>>>(k_e, Abf, 1048576);
  gemm128<0><<<dim3(64, 8), 256, 0, stream>>>(Abf, PW + 1 * 1048576, bke, Kep, 512);
  // v_e
  cvt_bf16<<<4096, 256, 0, stream>>>(v_e, Abf, 1048576);
  gemm128<1><<<dim3(64, 8), 256, 0, stream>>>(Abf, PW + 2 * 1048576, bve, Vte, 512);
  // k_i
  cvt_bf16<<<2048, 256, 0, stream>>>(k_i, Abf, 524288);
  gemm128<0><<<dim3(32, 8), 256, 0, stream>>>(Abf, PW + 3 * 1048576, bki, Kip, 256);
  // v_i
  cvt_bf16<<<2048, 256, 0, stream>>>(v_i, Abf, 524288);
  gemm128<1><<<dim3(32, 8), 256, 0, stream>>>(Abf, PW + 4 * 1048576, bvi, Vti, 256);
  // k_ei
  cvt_bf16<<<6144, 256, 0, stream>>>(k_ei, Abf, 1572864);
  gemm128<0><<<dim3(96, 8), 256, 0, stream>>>(Abf, PW + 5 * 1048576, bkei, Keip, 768);
  // v_ei
  cvt_bf16<<<6144, 256, 0, stream>>>(v_ei, Abf, 1572864);
  gemm128<1><<<dim3(96, 8), 256, 0, stream>>>(Abf, PW + 6 * 1048576, bvei, Vtei, 768);

  // bitmasks (Abf region is free now)
  make_bits<<<dim3(2, 8192), 256, 0, stream>>>(mask_e,  pad_e,  bits_e,  512);
  make_bits<<<dim3(3, 8192), 256, 0, stream>>>(mask_ei, pad_ei, bits_ei, 768);

  attn2<512, true , 0><<<2048, 256, 0, stream>>>(Qp, Kep,  Vte,  bits_e,  aw_e, scores, nullptr);
  attn2<256, false, 1><<<2048, 256, 0, stream>>>(Qp, Kip,  Vti,  nullptr, aw_i, scores, nullptr);
  attn2<768, true , 2><<<2048, 256, 0, stream>>>(Qp, Keip, Vtei, bits_ei, nullptr, scores, concat);

  gemm128<2><<<dim3(64, 8), 256, 0, stream>>>(concat, PW + 7 * 1048576, bout, out0, 512);
}